// Round 1
// 115.035 us; speedup vs baseline: 1.0140x; 1.0140x over previous
//
#include <hip/hip_runtime.h>
#include <math.h>

// Shapes: B=8 S=1024 IN=768 H=8 F=64 ; M=B*S=8192, N=H*F=512, K=768
// Pipeline (3 kernels):
//   prep     : merged conv_w (W fp32 -> WbT bf16 [512][768] transpose, blocks 0..95)
//              + xconv (X fp32 -> Xb bf16 row-major streaming, blocks 96..607).
//   gemm_xw  : Xb x WbT -> WhT bf16 [bh][f][s] (MFMA) + fused src/dst epilogue.
//              NEW (this round): tile 128(M)x64(N), BK=64, grid (64,8)=512 blocks
//              (2/CU). Staging via global_load_lds width=16 with PRE-SWIZZLED
//              global source (rule #21: linear LDS dest + inv-swz source + swz
//              read). Same conflict-free layout as before: content(row,pb) =
//              global block pb^(row&7). T3-minimum 2-phase: STAGE(next) at loop
//              top, MFMA covers load latency, one vmcnt(0)+barrier per K-step.
//   gat_attn : unchanged from verified 116.6us version. i-tile 64 (wave=16 rows),
//              grid (64 bh, 16 i); P-scores in MFMA A-frags; PV + l (ones-B) on
//              the MFMA pipe; double-buffered LDS, 1 barrier/tile; XCD = bh%8.

typedef __attribute__((ext_vector_type(8))) short short8;   // 8 bf16 (4 VGPRs)
typedef __attribute__((ext_vector_type(4))) float floatx4;  // MFMA C/D

union Frag { short8 s8; uint4 u4; };

__device__ inline unsigned as_u(float f) { union { float f; unsigned u; } v; v.f = f; return v.u; }
__device__ inline float as_f(unsigned u) { union { unsigned u; float f; } v; v.u = u; return v.f; }

// RNE pack two fp32 -> bf16x2 (lo = a, hi = b)
__device__ inline unsigned pk_rne(float a, float b) {
  unsigned ua = as_u(a); ua = ua + 0x7fffu + ((ua >> 16) & 1u);
  unsigned ub = as_u(b); ub = ub + 0x7fffu + ((ub >> 16) & 1u);
  return (ua >> 16) | (ub & 0xffff0000u);
}
__device__ inline unsigned short f2bf(float f) {
  unsigned u = as_u(f); u = u + 0x7fffu + ((u >> 16) & 1u);
  return (unsigned short)(u >> 16);
}

typedef __attribute__((address_space(3))) unsigned lds_u32;
typedef const __attribute__((address_space(1))) unsigned glb_u32;
__device__ inline void gload16(const void* g, void* l) {
  // async global->LDS, 16B/lane; LDS dest = wave-uniform base + lane*16
  __builtin_amdgcn_global_load_lds((glb_u32*)g, (lds_u32*)l, 16, 0, 0);
}

// ---------------- prep: conv_w (blocks 0..95) + xconv (blocks 96..607)
__global__ __launch_bounds__(256) void prep(const float* __restrict__ W,
                                            unsigned short* __restrict__ WbT,
                                            const float* __restrict__ X,
                                            unsigned short* __restrict__ Xb) {
  int t = threadIdx.x;
  if (blockIdx.x < 96) {
    // W fp32 [768][512] -> WbT bf16 [512][768] (transpose)
    __shared__ unsigned short tile[64][72];  // [n][k], stride 144B (bank-friendly)
    int kt = blockIdx.x >> 3, nt = blockIdx.x & 7;
    int k0 = kt * 64, n0 = nt * 64;
    int kr = t >> 2, cs = (t & 3) * 16;
#pragma unroll
    for (int q = 0; q < 4; q++) {
      float4 v = *(const float4*)&W[(k0 + kr) * 512 + n0 + cs + q * 4];
      tile[cs + q * 4 + 0][kr] = f2bf(v.x);
      tile[cs + q * 4 + 1][kr] = f2bf(v.y);
      tile[cs + q * 4 + 2][kr] = f2bf(v.z);
      tile[cs + q * 4 + 3][kr] = f2bf(v.w);
    }
    __syncthreads();
    int nr = t >> 2, ks = (t & 3) * 16;
    uint4 d0 = *(const uint4*)&tile[nr][ks];
    uint4 d1 = *(const uint4*)&tile[nr][ks + 8];
    *(uint4*)&WbT[(n0 + nr) * 768 + k0 + ks] = d0;
    *(uint4*)&WbT[(n0 + nr) * 768 + k0 + ks + 8] = d1;
  } else {
    // X fp32 (8192x768) -> Xb bf16 row-major. Streaming.
    const int total = 8192 * 768 / 8;  // 786432 uint4 outputs
    int stride = 512 * 256;
    for (int i = (blockIdx.x - 96) * 256 + t; i < total; i += stride) {
      float4 v0 = *(const float4*)&X[i * 8];
      float4 v1 = *(const float4*)&X[i * 8 + 4];
      uint4 o;
      o.x = pk_rne(v0.x, v0.y); o.y = pk_rne(v0.z, v0.w);
      o.z = pk_rne(v1.x, v1.y); o.w = pk_rne(v1.z, v1.w);
      *(uint4*)&Xb[i * 8] = o;
    }
  }
}

// ---------------- gemm_xw: Wh = Xb @ W (bf16 MFMA) + fused src/dst epilogue.
// tile 128(M) x 64(N), BK=64, 12 k-iters, grid (64 m, 8 n) = 512 blocks (2/CU),
// 256 thr = 4 waves; wave tile 64x32 -> acc[4][2], 16 MFMA/k-iter/wave.
// Staging: 24 global_load_lds_dwordx4 per block per iter (A:16, B:8; 6/wave).
// LDS dest linear (instr ai covers rows ai*8..ai*8+7, lane l -> row ai*8+(l>>3),
// 16B-block l&7); global source pre-swizzled so content(row,pb) = global block
// pb^(row&7); frag reads use (kb^(row&7)) -> conflict-free (2-way max, free).
__global__ __launch_bounds__(256) void gemm_xw(const unsigned short* __restrict__ Xb,
                                               const unsigned short* __restrict__ WbT,
                                               const float* __restrict__ a,
                                               const int* __restrict__ mask,
                                               unsigned short* __restrict__ WhT,
                                               float* __restrict__ srcT,
                                               float* __restrict__ dstT) {
  __shared__ unsigned short Asm[2][128 * 64];  // [buf][m][k] bf16, 16KB each
  __shared__ unsigned short Bsm[2][64 * 64];   // [buf][n][k] bf16, 8KB each
  __shared__ float sd[2][128], dd[2][128];     // fused src/dst cross-wave partials
  int t = threadIdx.x, w = t >> 6, lane = t & 63;
  int quad = lane >> 4, l15 = lane & 15;
  int m0 = blockIdx.x * 128, n0 = blockIdx.y * 64;
  int wm = (w & 1) * 64, wn = (w >> 1) * 32;

  floatx4 acc[4][2];
#pragma unroll
  for (int mt = 0; mt < 4; mt++)
#pragma unroll
    for (int nt = 0; nt < 2; nt++)
#pragma unroll
      for (int r = 0; r < 4; r++) acc[mt][nt][r] = 0.f;

  // staging source pointers (pre-swizzled): lane l covers row +(l>>3), block
  // (l&7)^(l>>3); wave w owns A-instrs w*4..w*4+3 (rows w*32+..), B-instrs
  // w*2..w*2+1 (rows w*16+..)
  int lr = lane >> 3;
  int cb = (lane & 7) ^ lr;
  const unsigned short* pa[4];
  const unsigned short* pb[2];
#pragma unroll
  for (int i = 0; i < 4; i++)
    pa[i] = &Xb[(m0 + w * 32 + i * 8 + lr) * 768 + cb * 8];
#pragma unroll
  for (int i = 0; i < 2; i++)
    pb[i] = &WbT[(n0 + w * 16 + i * 8 + lr) * 768 + cb * 8];

#define STAGE(bsel)                                                   \
  do {                                                                \
    unsigned short* dA = &Asm[bsel][w * 2048];                        \
    unsigned short* dB = &Bsm[bsel][w * 1024];                        \
    _Pragma("unroll") for (int i = 0; i < 4; i++) {                   \
      gload16(pa[i], dA + i * 512);                                   \
      pa[i] += 64;                                                    \
    }                                                                 \
    _Pragma("unroll") for (int i = 0; i < 2; i++) {                   \
      gload16(pb[i], dB + i * 512);                                   \
      pb[i] += 64;                                                    \
    }                                                                 \
  } while (0)

  // frag read addressing: row ra = wm+mt*16+l15 (A) / wn+nt*16+l15 (B);
  // ra&7 == l15&7 for all mt/nt (wm,wn,16 are multiples of 8) -> one key.
  int key = l15 & 7;
  int rA[4], rB[2];
#pragma unroll
  for (int mt = 0; mt < 4; mt++) rA[mt] = (wm + mt * 16 + l15) * 64;
#pragma unroll
  for (int nt = 0; nt < 2; nt++) rB[nt] = (wn + nt * 16 + l15) * 64;

  // prologue: stage tile 0, drain, barrier
  STAGE(0);
  __syncthreads();

#pragma unroll 2
  for (int kc = 0; kc < 12; kc++) {
    const int cur = kc & 1;
    // issue next tile's loads; they fly across the MFMA phase, drained by the
    // compiler's vmcnt(0) at the end-of-iter barrier (T3-minimum recipe)
    if (kc < 11) STAGE(cur ^ 1);
    const unsigned short* bufA = &Asm[cur][0];
    const unsigned short* bufB = &Bsm[cur][0];
#pragma unroll
    for (int kc2 = 0; kc2 < 2; kc2++) {
      int kb = kc2 * 4 + quad;
      int ko = (kb ^ key) * 8;
      Frag fa[4], fb[2];
#pragma unroll
      for (int mt = 0; mt < 4; mt++) fa[mt] = *(const Frag*)&bufA[rA[mt] + ko];
#pragma unroll
      for (int nt = 0; nt < 2; nt++) fb[nt] = *(const Frag*)&bufB[rB[nt] + ko];
#pragma unroll
      for (int mt = 0; mt < 4; mt++)
#pragma unroll
        for (int nt = 0; nt < 2; nt++)
          acc[mt][nt] = __builtin_amdgcn_mfma_f32_16x16x32_bf16(fa[mt].s8, fb[nt].s8,
                                                                acc[mt][nt], 0, 0, 0);
    }
    __syncthreads();
  }
#undef STAGE

  int h = n0 >> 6;  // n-tile is 64-aligned: whole block is one head
  // ---- store WhT: D row = quad*4+r (m), col = l15 (f); 4 consecutive s as bf16x4
#pragma unroll
  for (int mt = 0; mt < 4; mt++) {
#pragma unroll
    for (int nt = 0; nt < 2; nt++) {
      int f = wn + nt * 16 + l15;
      int m = m0 + wm + mt * 16 + quad * 4;
      int b = m >> 10, s = m & 1023;
      floatx4 cc = acc[mt][nt];
      uint2 st;
      st.x = pk_rne(cc[0], cc[1]);
      st.y = pk_rne(cc[2], cc[3]);
      *(uint2*)&WhT[((b * 8 + h) * 64 + f) * 1024 + s] = st;
    }
  }
  // ---- fused src/dst: reduce over l15 lanes, then the 2 wn-halves via LDS
  {
    float asv[2] = {a[wn + l15], a[wn + 16 + l15]};
    float adv[2] = {a[64 + wn + l15], a[64 + wn + 16 + l15]};
    float psrc[4][4], pdst[4][4];
#pragma unroll
    for (int mt = 0; mt < 4; mt++)
#pragma unroll
      for (int r = 0; r < 4; r++) {
        psrc[mt][r] = acc[mt][0][r] * asv[0] + acc[mt][1][r] * asv[1];
        pdst[mt][r] = acc[mt][0][r] * adv[0] + acc[mt][1][r] * adv[1];
      }
#pragma unroll
    for (int off = 1; off < 16; off <<= 1)
#pragma unroll
      for (int mt = 0; mt < 4; mt++)
#pragma unroll
        for (int r = 0; r < 4; r++) {
          psrc[mt][r] += __shfl_xor(psrc[mt][r], off);
          pdst[mt][r] += __shfl_xor(pdst[mt][r], off);
        }
    if (l15 == 0) {
      int half = w >> 1;  // wn half (w=0,1 -> wn 0 ; w=2,3 -> wn 32)
#pragma unroll
      for (int mt = 0; mt < 4; mt++)
#pragma unroll
        for (int r = 0; r < 4; r++) {
          int m = wm + mt * 16 + quad * 4 + r;
          sd[half][m] = psrc[mt][r];
          dd[half][m] = pdst[mt][r];
        }
    }
    __syncthreads();
    if (t < 128) {
      int m = m0 + t;
      int b = m >> 10, s = m & 1023;
      float sv = sd[0][t] + sd[1][t];
      float dvv = dd[0][t] + dd[1][t];
      srcT[(b * 8 + h) * 1024 + s] = sv;
      dstT[(b * 8 + h) * 1024 + s] = mask[b * 1024 + s] ? dvv : -1e30f;
    }
  }
}

// ---------------- gat_attn: i-tile 64, wave = 16 rows, 4 blocks/CU (R10 best).
// grid (64 bh, 16 i) = 1024 blocks -> XCD = bh%8 (Wh slice L2-local);
// 256 thr = 4 waves -> 16 waves/CU. Double-buffered LDS, ONE barrier per
// tile, loads never in flight at a barrier. l via ones-B MFMA (sums exactly
// the bf16-truncated p; lacc rows = acc rows). |e|<~1 so exp can't overflow;
// mask pre-folded into dstT as -1e30.
__global__ __launch_bounds__(256) void gat_attn(const unsigned short* __restrict__ WhT,
                                                const float* __restrict__ srcT,
                                                const float* __restrict__ dstT,
                                                float* __restrict__ out) {
  __shared__ unsigned short Bs[2][64 * 64];  // [buf][f][j] bf16, swizzle pb = kb^(f&7)
  int t = threadIdx.x, w = t >> 6, lane = t & 63;
  int quad = lane >> 4, l15 = lane & 15;
  int bh = blockIdx.x, b = bh >> 3;
  int iw = blockIdx.y * 64 + w * 16;

  floatx4 acc[4], lacc;
#pragma unroll
  for (int ft = 0; ft < 4; ft++)
#pragma unroll
    for (int r = 0; r < 4; r++) acc[ft][r] = 0.f;
#pragma unroll
  for (int r = 0; r < 4; r++) lacc[r] = 0.f;

  float src_r = srcT[bh * 1024 + iw + l15];

  Frag ones;
  ones.u4.x = 0x3F803F80u; ones.u4.y = 0x3F803F80u;
  ones.u4.z = 0x3F803F80u; ones.u4.w = 0x3F803F80u;

  const unsigned short* Wg = WhT + bh * 64 * 1024;
  const float* dbase = &dstT[bh * 1024 + quad * 8];
  int sf0 = t >> 3, skb = t & 7;    // staging: f rows {sf0, sf0+32}, 16B block idx
  int swz = (skb ^ (sf0 & 7)) * 8;  // (sf0+32)&7 == sf0&7

  // preload tile 0
  uint4 g0 = *(const uint4*)&Wg[sf0 * 1024 + skb * 8];
  uint4 g1 = *(const uint4*)&Wg[(sf0 + 32) * 1024 + skb * 8];
  float4 dv[4];
  dv[0] = *(const float4*)&dbase[0];
  dv[1] = *(const float4*)&dbase[4];
  dv[2] = *(const float4*)&dbase[32];
  dv[3] = *(const float4*)&dbase[36];

#pragma unroll 2
  for (int jt = 0; jt < 16; jt++) {
    int j0 = jt * 64;
    unsigned short* buf = &Bs[jt & 1][0];
    // stage tile jt (g landed during the previous iter's scores+MFMA)
    *(uint4*)&buf[sf0 * 64 + swz] = g0;
    *(uint4*)&buf[(sf0 + 32) * 64 + swz] = g1;
    __syncthreads();  // nothing in flight here
    // issue tile jt+1 loads; consumed before the NEXT barrier
    float4 ndv[4] = {dv[0], dv[1], dv[2], dv[3]};
    if (jt < 15) {
      g0 = *(const uint4*)&Wg[sf0 * 1024 + j0 + 64 + skb * 8];
      g1 = *(const uint4*)&Wg[(sf0 + 32) * 1024 + j0 + 64 + skb * 8];
      ndv[0] = *(const float4*)&dbase[j0 + 64];
      ndv[1] = *(const float4*)&dbase[j0 + 68];
      ndv[2] = *(const float4*)&dbase[j0 + 96];
      ndv[3] = *(const float4*)&dbase[j0 + 100];
    }
    // scores tile jt -> A-fragments (VALU; covers the just-issued loads)
    Frag fragA[2];
#pragma unroll
    for (int jc = 0; jc < 2; jc++) {
      float dj[8] = {dv[jc * 2].x, dv[jc * 2].y, dv[jc * 2].z, dv[jc * 2].w,
                     dv[jc * 2 + 1].x, dv[jc * 2 + 1].y, dv[jc * 2 + 1].z, dv[jc * 2 + 1].w};
      unsigned pw[4];
#pragma unroll
      for (int pr = 0; pr < 4; pr++) {
        float x0 = src_r + dj[pr * 2];
        float x1 = src_r + dj[pr * 2 + 1];
        x0 = fmaxf(x0, 0.2f * x0);  // leaky_relu (alpha<1)
        x1 = fmaxf(x1, 0.2f * x1);
        float p0 = __expf(x0), p1 = __expf(x1);
        pw[pr] = __builtin_amdgcn_perm(as_u(p1), as_u(p0), 0x07060302u);  // bf16x2
      }
      fragA[jc].u4.x = pw[0];
      fragA[jc].u4.y = pw[1];
      fragA[jc].u4.z = pw[2];
      fragA[jc].u4.w = pw[3];
    }
    // MFMA tile jt: acc[ft] += P(16x32) x Wh(32x16) ; lacc += P x ones
#pragma unroll
    for (int jc = 0; jc < 2; jc++) {
      Frag fbr[4];
#pragma unroll
      for (int ft = 0; ft < 4; ft++) {
        int f = ft * 16 + l15;
        int kb = jc * 4 + quad;
        fbr[ft] = *(const Frag*)&buf[f * 64 + (kb ^ (f & 7)) * 8];
      }
#pragma unroll
      for (int ft = 0; ft < 4; ft++)
        acc[ft] = __builtin_amdgcn_mfma_f32_16x16x32_bf16(fragA[jc].s8, fbr[ft].s8,
                                                          acc[ft], 0, 0, 0);
      lacc = __builtin_amdgcn_mfma_f32_16x16x32_bf16(fragA[jc].s8, ones.s8, lacc, 0, 0, 0);
    }
#pragma unroll
    for (int q = 0; q < 4; q++) dv[q] = ndv[q];
  }
  // epilogue: C row = quad*4+r, col = l15; lacc rows align with acc rows
  float inv[4] = {1.f / lacc[0], 1.f / lacc[1], 1.f / lacc[2], 1.f / lacc[3]};
  int mrow = b * 1024 + iw + quad * 4;
#pragma unroll
  for (int ft = 0; ft < 4; ft++) {
    int col = (bh & 7) * 64 + ft * 16 + l15;
#pragma unroll
    for (int r = 0; r < 4; r++)
      out[(mrow + r) * 512 + col] = acc[ft][r] * inv[r];
  }
}

extern "C" void kernel_launch(void* const* d_in, const int* in_sizes, int n_in,
                              void* d_out, int out_size, void* d_ws, size_t ws_size,
                              hipStream_t stream) {
  const float* X = (const float*)d_in[0];   // (8,1024,768)
  const int* mask = (const int*)d_in[1];    // (8,1024)
  const float* W = (const float*)d_in[2];   // (768,512)
  const float* a = (const float*)d_in[3];   // (128,)
  float* out = (float*)d_out;               // (8,1024,512)

  char* ws = (char*)d_ws;
  unsigned short* WhT = (unsigned short*)ws;                    // 64*64*1024 bf16 = 8388608 B
  unsigned short* WbT = (unsigned short*)(ws + 8388608);        // 512*768 bf16  = 786432 B
  float* srcT = (float*)(ws + 9175040);                         // 64*1024 f32   = 262144 B
  float* dstT = (float*)(ws + 9437184);                         // 64*1024 f32   = 262144 B
  unsigned short* Xb = (unsigned short*)(ws + 9699328);         // 8192*768 bf16 = 12582912 B

  prep<<<608, 256, 0, stream>>>(W, WbT, X, Xb);
  gemm_xw<<<dim3(64, 8), 256, 0, stream>>>(Xb, WbT, a, mask, WhT, srcT, dstT);
  gat_attn<<<dim3(64, 16), 256, 0, stream>>>(WhT, srcT, dstT, out);
}